// Round 1
// baseline (145.636 us; speedup 1.0000x reference)
//
#include <hip/hip_runtime.h>
#include <hip/hip_bf16.h>

typedef unsigned short ushort_t;
typedef unsigned int uint_t;
typedef __attribute__((ext_vector_type(8))) short short8;
typedef __attribute__((ext_vector_type(4))) float f32x4;

#define FOLD 128
#define DELTA (30.0f / 63.0f)
#define COEFF (-2.205f)   /* -0.5 / (30/63)^2 = -3969/1800 */

__device__ __forceinline__ ushort_t f2bf(float f) {
    // round-to-nearest-even bf16 (values here are finite, no NaN handling needed)
    uint_t x = __builtin_bit_cast(uint_t, f);
    x += 0x7FFFu + ((x >> 16) & 1u);
    return (ushort_t)(x >> 16);
}

// Pack W1 (320x128) and W2 (128x128) fp32 row-major into bf16 MFMA-B-fragment order:
// flat index i = ((ks*8 + nt)*64 + lane)*8 + j  <->  W[ks*32 + (lane>>4)*8 + j][nt*16 + (lane&15)]
__global__ __launch_bounds__(256) void pack_w(const float* __restrict__ W1,
                                              const float* __restrict__ W2,
                                              ushort_t* __restrict__ W1p,
                                              ushort_t* __restrict__ W2p) {
    int i = blockIdx.x * 256 + threadIdx.x;
    if (i < 40960) {
        int j = i & 7, l = (i >> 3) & 63, nt = (i >> 9) & 7, ks = i >> 12;
        int row = ks * 32 + ((l >> 4) << 3) + j;
        int col = nt * 16 + (l & 15);
        W1p[i] = f2bf(W1[row * FOLD + col]);
    } else if (i < 40960 + 16384) {
        int q = i - 40960;
        int j = q & 7, l = (q >> 3) & 63, nt = (q >> 9) & 7, ks = q >> 12;
        int row = ks * 32 + ((l >> 4) << 3) + j;
        int col = nt * 16 + (l & 15);
        W2p[q] = f2bf(W2[row * FOLD + col]);
    }
}

__global__ __launch_bounds__(256) void fused(
    const float* __restrict__ lig,
    const float* __restrict__ p0, const float* __restrict__ p1,
    const float* __restrict__ p2, const float* __restrict__ p3,
    const float* __restrict__ p4,
    const ushort_t* __restrict__ W1p, const ushort_t* __restrict__ W2p,
    const float* __restrict__ b1, const float* __restrict__ b2,
    const int* __restrict__ src, const int* __restrict__ dst,
    float* __restrict__ out, int E)
{
    __shared__ float d_lds[5][32];
    __shared__ ushort_t attr[32][328];   // 320 + 8 pad: row stride 656B = 164 dwords (4-dword bank skew)
    __shared__ ushort_t h_lds[32][136];  // 128 + 8 pad

    const int t = threadIdx.x;
    const int e0 = blockIdx.x * 32;

    // ---- Phase 1: distances (5 channels x 32 edges) ----
    if (t < 160) {
        int m = t & 31, c = t >> 5;
        int e = e0 + m;
        if (e >= E) e = E - 1;
        int s = src[e], dd = dst[e];
        const float* P = (c == 0) ? p0 : (c == 1) ? p1 : (c == 2) ? p2 : (c == 3) ? p3 : p4;
        float dx = lig[3 * s]     - P[3 * dd];
        float dy = lig[3 * s + 1] - P[3 * dd + 1];
        float dz = lig[3 * s + 2] - P[3 * dd + 2];
        d_lds[c][m] = sqrtf(dx * dx + dy * dy + dz * dz);
    }
    __syncthreads();

    // ---- Phase 2: RBF expansion -> bf16 attr tile (each thread: 1 edge row x 40 k's) ----
    {
        int m = t >> 3;
        int k0 = (t & 7) * 40;
        #pragma unroll
        for (int kk = 0; kk < 40; kk += 2) {
            int k = k0 + kk;
            int c = k >> 6, r = k & 63;
            float d = d_lds[c][m];
            float x0 = d - (float)r * DELTA;
            float x1 = x0 - DELTA;
            float v0 = __expf(COEFF * x0 * x0);
            float v1 = __expf(COEFF * x1 * x1);
            uint_t u = (uint_t)f2bf(v0) | ((uint_t)f2bf(v1) << 16);
            *reinterpret_cast<uint_t*>(&attr[m][k]) = u;
        }
    }
    __syncthreads();

    const int w = t >> 6;        // wave id: owns output cols [w*32, w*32+32)
    const int l = t & 63;
    const int lrow = l & 15, lgrp = l >> 4;

    // ---- Phase 3: GEMM1 [32x320]@[320x128] via mfma_f32_16x16x32_bf16 ----
    f32x4 acc00 = {0.f, 0.f, 0.f, 0.f}, acc01 = {0.f, 0.f, 0.f, 0.f};
    f32x4 acc10 = {0.f, 0.f, 0.f, 0.f}, acc11 = {0.f, 0.f, 0.f, 0.f};
    const short8* W1v = reinterpret_cast<const short8*>(W1p);
    #pragma unroll
    for (int ks = 0; ks < 10; ++ks) {
        short8 a0 = *reinterpret_cast<const short8*>(&attr[lrow][ks * 32 + lgrp * 8]);
        short8 a1 = *reinterpret_cast<const short8*>(&attr[lrow + 16][ks * 32 + lgrp * 8]);
        short8 bA = W1v[(ks * 8 + w * 2 + 0) * 64 + l];
        short8 bB = W1v[(ks * 8 + w * 2 + 1) * 64 + l];
        acc00 = __builtin_amdgcn_mfma_f32_16x16x32_bf16(a0, bA, acc00, 0, 0, 0);
        acc01 = __builtin_amdgcn_mfma_f32_16x16x32_bf16(a0, bB, acc01, 0, 0, 0);
        acc10 = __builtin_amdgcn_mfma_f32_16x16x32_bf16(a1, bA, acc10, 0, 0, 0);
        acc11 = __builtin_amdgcn_mfma_f32_16x16x32_bf16(a1, bB, acc11, 0, 0, 0);
    }

    // bias + relu + pack h to LDS (C/D layout: row=(lane>>4)*4+j, col=lane&15)
    {
        float bv0 = b1[w * 32 + lrow];
        float bv1 = b1[w * 32 + 16 + lrow];
        #pragma unroll
        for (int j = 0; j < 4; ++j) {
            int r0 = lgrp * 4 + j;
            h_lds[r0][w * 32 + lrow]           = f2bf(fmaxf(acc00[j] + bv0, 0.f));
            h_lds[r0][w * 32 + 16 + lrow]      = f2bf(fmaxf(acc01[j] + bv1, 0.f));
            h_lds[r0 + 16][w * 32 + lrow]      = f2bf(fmaxf(acc10[j] + bv0, 0.f));
            h_lds[r0 + 16][w * 32 + 16 + lrow] = f2bf(fmaxf(acc11[j] + bv1, 0.f));
        }
    }
    __syncthreads();

    // ---- Phase 4: GEMM2 [32x128]@[128x128] ----
    f32x4 o00 = {0.f, 0.f, 0.f, 0.f}, o01 = {0.f, 0.f, 0.f, 0.f};
    f32x4 o10 = {0.f, 0.f, 0.f, 0.f}, o11 = {0.f, 0.f, 0.f, 0.f};
    const short8* W2v = reinterpret_cast<const short8*>(W2p);
    #pragma unroll
    for (int ks = 0; ks < 4; ++ks) {
        short8 a0 = *reinterpret_cast<const short8*>(&h_lds[lrow][ks * 32 + lgrp * 8]);
        short8 a1 = *reinterpret_cast<const short8*>(&h_lds[lrow + 16][ks * 32 + lgrp * 8]);
        short8 bA = W2v[(ks * 8 + w * 2 + 0) * 64 + l];
        short8 bB = W2v[(ks * 8 + w * 2 + 1) * 64 + l];
        o00 = __builtin_amdgcn_mfma_f32_16x16x32_bf16(a0, bA, o00, 0, 0, 0);
        o01 = __builtin_amdgcn_mfma_f32_16x16x32_bf16(a0, bB, o01, 0, 0, 0);
        o10 = __builtin_amdgcn_mfma_f32_16x16x32_bf16(a1, bA, o10, 0, 0, 0);
        o11 = __builtin_amdgcn_mfma_f32_16x16x32_bf16(a1, bB, o11, 0, 0, 0);
    }

    // ---- Phase 5: bias + store fp32 ----
    {
        float c0 = b2[w * 32 + lrow];
        float c1 = b2[w * 32 + 16 + lrow];
        #pragma unroll
        for (int j = 0; j < 4; ++j) {
            int r0 = lgrp * 4 + j;
            int eA = e0 + r0;
            int eB = e0 + r0 + 16;
            if (eA < E) {
                out[(size_t)eA * FOLD + w * 32 + lrow]      = o00[j] + c0;
                out[(size_t)eA * FOLD + w * 32 + 16 + lrow] = o01[j] + c1;
            }
            if (eB < E) {
                out[(size_t)eB * FOLD + w * 32 + lrow]      = o10[j] + c0;
                out[(size_t)eB * FOLD + w * 32 + 16 + lrow] = o11[j] + c1;
            }
        }
    }
}

extern "C" void kernel_launch(void* const* d_in, const int* in_sizes, int n_in,
                              void* d_out, int out_size, void* d_ws, size_t ws_size,
                              hipStream_t stream) {
    const float* lig = (const float*)d_in[0];
    const float* p0  = (const float*)d_in[1];
    const float* p1  = (const float*)d_in[2];
    const float* p2  = (const float*)d_in[3];
    const float* p3  = (const float*)d_in[4];
    const float* p4  = (const float*)d_in[5];
    const float* W1  = (const float*)d_in[6];
    const float* b1  = (const float*)d_in[7];
    const float* W2  = (const float*)d_in[8];
    const float* b2  = (const float*)d_in[9];
    const int* src   = (const int*)d_in[10];
    const int* dst   = (const int*)d_in[11];
    float* out = (float*)d_out;
    const int E = in_sizes[10];

    ushort_t* W1p = (ushort_t*)d_ws;
    ushort_t* W2p = W1p + 40960;

    pack_w<<<(40960 + 16384 + 255) / 256, 256, 0, stream>>>(W1, W2, W1p, W2p);

    int tiles = (E + 31) / 32;
    fused<<<tiles, 256, 0, stream>>>(lig, p0, p1, p2, p3, p4, W1p, W2p,
                                     b1, b2, src, dst, out, E);
}

// Round 3
// 138.607 us; speedup vs baseline: 1.0507x; 1.0507x over previous
//
#include <hip/hip_runtime.h>
#include <hip/hip_bf16.h>

typedef unsigned short ushort_t;
typedef unsigned int uint_t;
typedef __attribute__((ext_vector_type(8))) short short8;
typedef __attribute__((ext_vector_type(4))) float f32x4;
typedef __attribute__((ext_vector_type(4))) uint_t uint4_t;

#define FOLD 128
// exp(COEFF*x^2) = 2^(-(x*S)^2);  S = sqrt(0.5/ln2)/DELTA, DELTA = 30/63
#define S_CONST 1.78357580f
#define DS_CONST 0.84932180f   /* DELTA * S_CONST = sqrt(0.5/ln2) */

__device__ __forceinline__ ushort_t f2bf(float f) {
    // round-to-nearest-even bf16 (finite positive values here)
    uint_t x = __builtin_bit_cast(uint_t, f);
    x += 0x7FFFu + ((x >> 16) & 1u);
    return (ushort_t)(x >> 16);
}

__device__ __forceinline__ uint_t pack2bf(float flo, float fhi) {
    // dword = bf16(fhi)<<16 | bf16(flo), RNE. ~8 VALU ops (add3 + and_or fused).
    uint_t xl = __builtin_bit_cast(uint_t, flo);
    uint_t xh = __builtin_bit_cast(uint_t, fhi);
    uint_t rl = (xl + 0x7FFFu + ((xl >> 16) & 1u)) >> 16;
    uint_t rh = (xh + 0x7FFFu + ((xh >> 16) & 1u)) & 0xFFFF0000u;
    return rh | rl;
}

// Pack W1 (320x128) and W2 (128x128) fp32 row-major into bf16 MFMA-B-fragment order:
// flat index i = ((ks*8 + nt)*64 + lane)*8 + j  <->  W[ks*32 + (lane>>4)*8 + j][nt*16 + (lane&15)]
__global__ __launch_bounds__(256) void pack_w(const float* __restrict__ W1,
                                              const float* __restrict__ W2,
                                              ushort_t* __restrict__ W1p,
                                              ushort_t* __restrict__ W2p) {
    int i = blockIdx.x * 256 + threadIdx.x;
    if (i < 40960) {
        int j = i & 7, l = (i >> 3) & 63, nt = (i >> 9) & 7, ks = i >> 12;
        int row = ks * 32 + ((l >> 4) << 3) + j;
        int col = nt * 16 + (l & 15);
        W1p[i] = f2bf(W1[row * FOLD + col]);
    } else if (i < 40960 + 16384) {
        int q = i - 40960;
        int j = q & 7, l = (q >> 3) & 63, nt = (q >> 9) & 7, ks = q >> 12;
        int row = ks * 32 + ((l >> 4) << 3) + j;
        int col = nt * 16 + (l & 15);
        W2p[q] = f2bf(W2[row * FOLD + col]);
    }
}

__global__ __launch_bounds__(256) void fused(
    const float* __restrict__ lig,
    const float* __restrict__ p0, const float* __restrict__ p1,
    const float* __restrict__ p2, const float* __restrict__ p3,
    const float* __restrict__ p4,
    const ushort_t* __restrict__ W1p, const ushort_t* __restrict__ W2p,
    const float* __restrict__ b1, const float* __restrict__ b2,
    const int* __restrict__ src, const int* __restrict__ dst,
    float* __restrict__ out, int E)
{
    __shared__ float d_lds[5][32];
    __shared__ alignas(16) uint_t attrU[32 * 160];  // [32 edges][320 k] bf16, dword-major, XOR-swizzled
    __shared__ ushort_t h_lds[32][136];             // 128 + 8 pad

    const int t = threadIdx.x;
    const int e0 = blockIdx.x * 32;

    // ---- Phase 1: distances (5 channels x 32 edges) ----
    if (t < 160) {
        int m = t & 31, c = t >> 5;
        int e = e0 + m;
        if (e >= E) e = E - 1;
        int s = src[e], dd = dst[e];
        const float* P = (c == 0) ? p0 : (c == 1) ? p1 : (c == 2) ? p2 : (c == 3) ? p3 : p4;
        float dx = lig[3 * s]     - P[3 * dd];
        float dy = lig[3 * s + 1] - P[3 * dd + 1];
        float dz = lig[3 * s + 2] - P[3 * dd + 2];
        d_lds[c][m] = sqrtf(dx * dx + dy * dy + dz * dz);
    }
    __syncthreads();

    // ---- Phase 2: RBF expansion -> bf16 attr tile ----
    // thread t: edge m = t>>3, k-chunk q = t&7; handles k = 64c + 8q + i (c=0..4, i=0..7).
    // u = d*S - (8q+i)*DS; v = exp2(-u*u): 1 sub + 1 fma + 1 v_exp per element.
    {
        const int m = t >> 3;
        const int q = t & 7;
        const int swz = (m & 7) << 2;            // XOR on dword bits [4:2]
        const float ubase = (float)(8 * q) * DS_CONST;
        float dv[5];
        #pragma unroll
        for (int c = 0; c < 5; ++c) dv[c] = d_lds[c][m];
        #pragma unroll
        for (int c = 0; c < 5; ++c) {
            float u0 = __builtin_fmaf(dv[c], S_CONST, -ubase);
            uint4_t vals;
            #pragma unroll
            for (int i = 0; i < 4; ++i) {
                float ua = u0 - (float)(2 * i) * DS_CONST;
                float ub = u0 - (float)(2 * i + 1) * DS_CONST;
                float va = __builtin_amdgcn_exp2f(-(ua * ua));
                float vb = __builtin_amdgcn_exp2f(-(ub * ub));
                vals[i] = pack2bf(va, vb);
            }
            int o = 32 * c + 4 * q;              // dword offset within row (4-dword aligned)
            *reinterpret_cast<uint4_t*>(&attrU[m * 160 + (o ^ swz)]) = vals;
        }
    }
    __syncthreads();

    const int w = t >> 6;        // wave id: owns output cols [w*32, w*32+32)
    const int l = t & 63;
    const int lrow = l & 15, lgrp = l >> 4;
    const int aswz = (lrow & 7) << 2;

    // ---- Phase 3: GEMM1 [32x320]@[320x128] via mfma_f32_16x16x32_bf16 ----
    f32x4 acc00 = {0.f, 0.f, 0.f, 0.f}, acc01 = {0.f, 0.f, 0.f, 0.f};
    f32x4 acc10 = {0.f, 0.f, 0.f, 0.f}, acc11 = {0.f, 0.f, 0.f, 0.f};
    const short8* W1v = reinterpret_cast<const short8*>(W1p);
    #pragma unroll
    for (int ks = 0; ks < 10; ++ks) {
        int o = ks * 16 + lgrp * 4;
        short8 a0 = *reinterpret_cast<const short8*>(&attrU[lrow * 160 + (o ^ aswz)]);
        short8 a1 = *reinterpret_cast<const short8*>(&attrU[(lrow + 16) * 160 + (o ^ aswz)]);
        short8 bA = W1v[(ks * 8 + w * 2 + 0) * 64 + l];
        short8 bB = W1v[(ks * 8 + w * 2 + 1) * 64 + l];
        acc00 = __builtin_amdgcn_mfma_f32_16x16x32_bf16(a0, bA, acc00, 0, 0, 0);
        acc01 = __builtin_amdgcn_mfma_f32_16x16x32_bf16(a0, bB, acc01, 0, 0, 0);
        acc10 = __builtin_amdgcn_mfma_f32_16x16x32_bf16(a1, bA, acc10, 0, 0, 0);
        acc11 = __builtin_amdgcn_mfma_f32_16x16x32_bf16(a1, bB, acc11, 0, 0, 0);
    }

    // bias + relu + pack h to LDS (C/D layout: row=(lane>>4)*4+j, col=lane&15)
    {
        float bv0 = b1[w * 32 + lrow];
        float bv1 = b1[w * 32 + 16 + lrow];
        #pragma unroll
        for (int j = 0; j < 4; ++j) {
            int r0 = lgrp * 4 + j;
            h_lds[r0][w * 32 + lrow]           = f2bf(fmaxf(acc00[j] + bv0, 0.f));
            h_lds[r0][w * 32 + 16 + lrow]      = f2bf(fmaxf(acc01[j] + bv1, 0.f));
            h_lds[r0 + 16][w * 32 + lrow]      = f2bf(fmaxf(acc10[j] + bv0, 0.f));
            h_lds[r0 + 16][w * 32 + 16 + lrow] = f2bf(fmaxf(acc11[j] + bv1, 0.f));
        }
    }
    __syncthreads();

    // ---- Phase 4: GEMM2 [32x128]@[128x128] ----
    f32x4 o00 = {0.f, 0.f, 0.f, 0.f}, o01 = {0.f, 0.f, 0.f, 0.f};
    f32x4 o10 = {0.f, 0.f, 0.f, 0.f}, o11 = {0.f, 0.f, 0.f, 0.f};
    const short8* W2v = reinterpret_cast<const short8*>(W2p);
    #pragma unroll
    for (int ks = 0; ks < 4; ++ks) {
        short8 a0 = *reinterpret_cast<const short8*>(&h_lds[lrow][ks * 32 + lgrp * 8]);
        short8 a1 = *reinterpret_cast<const short8*>(&h_lds[lrow + 16][ks * 32 + lgrp * 8]);
        short8 bA = W2v[(ks * 8 + w * 2 + 0) * 64 + l];
        short8 bB = W2v[(ks * 8 + w * 2 + 1) * 64 + l];
        o00 = __builtin_amdgcn_mfma_f32_16x16x32_bf16(a0, bA, o00, 0, 0, 0);
        o01 = __builtin_amdgcn_mfma_f32_16x16x32_bf16(a0, bB, o01, 0, 0, 0);
        o10 = __builtin_amdgcn_mfma_f32_16x16x32_bf16(a1, bA, o10, 0, 0, 0);
        o11 = __builtin_amdgcn_mfma_f32_16x16x32_bf16(a1, bB, o11, 0, 0, 0);
    }

    // ---- Phase 5: bias + store fp32 ----
    {
        float c0 = b2[w * 32 + lrow];
        float c1 = b2[w * 32 + 16 + lrow];
        #pragma unroll
        for (int j = 0; j < 4; ++j) {
            int r0 = lgrp * 4 + j;
            int eA = e0 + r0;
            int eB = e0 + r0 + 16;
            if (eA < E) {
                out[(size_t)eA * FOLD + w * 32 + lrow]      = o00[j] + c0;
                out[(size_t)eA * FOLD + w * 32 + 16 + lrow] = o01[j] + c1;
            }
            if (eB < E) {
                out[(size_t)eB * FOLD + w * 32 + lrow]      = o10[j] + c0;
                out[(size_t)eB * FOLD + w * 32 + 16 + lrow] = o11[j] + c1;
            }
        }
    }
}

extern "C" void kernel_launch(void* const* d_in, const int* in_sizes, int n_in,
                              void* d_out, int out_size, void* d_ws, size_t ws_size,
                              hipStream_t stream) {
    const float* lig = (const float*)d_in[0];
    const float* p0  = (const float*)d_in[1];
    const float* p1  = (const float*)d_in[2];
    const float* p2  = (const float*)d_in[3];
    const float* p3  = (const float*)d_in[4];
    const float* p4  = (const float*)d_in[5];
    const float* W1  = (const float*)d_in[6];
    const float* b1  = (const float*)d_in[7];
    const float* W2  = (const float*)d_in[8];
    const float* b2  = (const float*)d_in[9];
    const int* src   = (const int*)d_in[10];
    const int* dst   = (const int*)d_in[11];
    float* out = (float*)d_out;
    const int E = in_sizes[10];

    ushort_t* W1p = (ushort_t*)d_ws;
    ushort_t* W2p = W1p + 40960;

    pack_w<<<(40960 + 16384 + 255) / 256, 256, 0, stream>>>(W1, W2, W1p, W2p);

    int tiles = (E + 31) / 32;
    fused<<<tiles, 256, 0, stream>>>(lig, p0, p1, p2, p3, p4, W1p, W2p,
                                     b1, b2, src, dst, out, E);
}

// Round 4
// 123.706 us; speedup vs baseline: 1.1773x; 1.1204x over previous
//
#include <hip/hip_runtime.h>
#include <hip/hip_bf16.h>

typedef unsigned short ushort_t;
typedef unsigned int uint_t;
typedef __attribute__((ext_vector_type(8))) short short8;
typedef __attribute__((ext_vector_type(4))) float f32x4;
typedef __attribute__((ext_vector_type(4))) uint_t uint4_t;

#define FOLD 128
// exp(COEFF*x^2) = 2^(-(x*S)^2);  S = sqrt(0.5/ln2)/DELTA, DELTA = 30/63
#define S_CONST 1.78357580f
#define DS_CONST 0.84932180f   /* DELTA * S_CONST = sqrt(0.5/ln2) */

__device__ __forceinline__ ushort_t f2bf(float f) {
    uint_t x = __builtin_bit_cast(uint_t, f);
    x += 0x7FFFu + ((x >> 16) & 1u);
    return (ushort_t)(x >> 16);
}

__device__ __forceinline__ uint_t pack2bf(float flo, float fhi) {
    uint_t xl = __builtin_bit_cast(uint_t, flo);
    uint_t xh = __builtin_bit_cast(uint_t, fhi);
    uint_t rl = (xl + 0x7FFFu + ((xl >> 16) & 1u)) >> 16;
    uint_t rh = (xh + 0x7FFFu + ((xh >> 16) & 1u)) & 0xFFFF0000u;
    return rh | rl;
}

// Pack W1 (320x128) and W2 (128x128) fp32 row-major into bf16 MFMA-B-fragment order:
// flat index i = ((ks*8 + nt)*64 + lane)*8 + j  <->  W[ks*32 + (lane>>4)*8 + j][nt*16 + (lane&15)]
__global__ __launch_bounds__(256) void pack_w(const float* __restrict__ W1,
                                              const float* __restrict__ W2,
                                              ushort_t* __restrict__ W1p,
                                              ushort_t* __restrict__ W2p) {
    int i = blockIdx.x * 256 + threadIdx.x;
    if (i < 40960) {
        int j = i & 7, l = (i >> 3) & 63, nt = (i >> 9) & 7, ks = i >> 12;
        int row = ks * 32 + ((l >> 4) << 3) + j;
        int col = nt * 16 + (l & 15);
        W1p[i] = f2bf(W1[row * FOLD + col]);
    } else if (i < 40960 + 16384) {
        int q = i - 40960;
        int j = q & 7, l = (q >> 3) & 63, nt = (q >> 9) & 7, ks = q >> 12;
        int row = ks * 32 + ((l >> 4) << 3) + j;
        int col = nt * 16 + (l & 15);
        W2p[q] = f2bf(W2[row * FOLD + col]);
    }
}

__global__ __launch_bounds__(256, 2) void fused(
    const float* __restrict__ lig,
    const float* __restrict__ p0, const float* __restrict__ p1,
    const float* __restrict__ p2, const float* __restrict__ p3,
    const float* __restrict__ p4,
    const ushort_t* __restrict__ W1p, const ushort_t* __restrict__ W2p,
    const float* __restrict__ b1, const float* __restrict__ b2,
    const int* __restrict__ src, const int* __restrict__ dst,
    float* __restrict__ out, int E)
{
    __shared__ float d_lds[2][5][32];
    __shared__ alignas(16) uint_t attrU[32 * 160];  // [32 edges][320 k] bf16 dwords, XOR-swizzled
    __shared__ ushort_t h_lds[32][136];             // 128 + 8 pad

    const int t = threadIdx.x;
    const int w = t >> 6;        // wave id: owns output cols [w*32, w*32+32)
    const int l = t & 63;
    const int lrow = l & 15, lgrp = l >> 4;
    const int aswz = (lrow & 7) << 2;
    const int ntiles = (E + 31) >> 5;

    // ---- Load per-wave W fragments into registers (once per block) ----
    const short8* W1v = reinterpret_cast<const short8*>(W1p);
    const short8* W2v = reinterpret_cast<const short8*>(W2p);
    short8 wb1[20], wb2[8];
    #pragma unroll
    for (int ks = 0; ks < 10; ++ks) {
        wb1[2 * ks]     = W1v[(ks * 8 + w * 2 + 0) * 64 + l];
        wb1[2 * ks + 1] = W1v[(ks * 8 + w * 2 + 1) * 64 + l];
    }
    #pragma unroll
    for (int ks = 0; ks < 4; ++ks) {
        wb2[2 * ks]     = W2v[(ks * 8 + w * 2 + 0) * 64 + l];
        wb2[2 * ks + 1] = W2v[(ks * 8 + w * 2 + 1) * 64 + l];
    }
    const float bv0 = b1[w * 32 + lrow];
    const float bv1 = b1[w * 32 + 16 + lrow];
    const float c0  = b2[w * 32 + lrow];
    const float c1  = b2[w * 32 + 16 + lrow];

    // gather-thread mapping (fixed per thread)
    const bool gth = (t < 160);
    const int gm = t & 31, gc = t >> 5;
    const float* P = (gc == 0) ? p0 : (gc == 1) ? p1 : (gc == 2) ? p2 : (gc == 3) ? p3 : p4;

    // exp-thread mapping
    const int m2 = t >> 3, q2 = t & 7;
    const int swz = (m2 & 7) << 2;
    const float ubase = (float)(8 * q2) * DS_CONST;

    int tile = blockIdx.x;
    if (tile >= ntiles) return;

    // ---- Prologue: gather tile 0 -> d_lds[0] ----
    if (gth) {
        int e = tile * 32 + gm; if (e >= E) e = E - 1;
        int s = src[e], dd = dst[e];
        float dx = lig[3 * s]     - P[3 * dd];
        float dy = lig[3 * s + 1] - P[3 * dd + 1];
        float dz = lig[3 * s + 2] - P[3 * dd + 2];
        d_lds[0][gc][gm] = sqrtf(dx * dx + dy * dy + dz * dz);
    }
    __syncthreads();

    int buf = 0;
    while (true) {
        const int next = tile + gridDim.x;
        const bool havenext = (next < ntiles);

        // ---- Issue next tile's gather loads (results used after exp work) ----
        float ax, ay, az, bx, by, bz;
        if (gth && havenext) {
            int e = next * 32 + gm; if (e >= E) e = E - 1;
            int s = src[e], dd = dst[e];
            ax = lig[3 * s];     bx = P[3 * dd];
            ay = lig[3 * s + 1]; by = P[3 * dd + 1];
            az = lig[3 * s + 2]; bz = P[3 * dd + 2];
        }

        // ---- Phase 2: RBF expansion d_lds[buf] -> attrU ----
        float dv[5];
        #pragma unroll
        for (int c = 0; c < 5; ++c) dv[c] = d_lds[buf][c][m2];
        #pragma unroll
        for (int c = 0; c < 5; ++c) {
            float u0 = __builtin_fmaf(dv[c], S_CONST, -ubase);
            uint4_t vals;
            #pragma unroll
            for (int i = 0; i < 4; ++i) {
                float ua = u0 - (float)(2 * i) * DS_CONST;
                float ub = u0 - (float)(2 * i + 1) * DS_CONST;
                float va = __builtin_amdgcn_exp2f(-(ua * ua));
                float vb = __builtin_amdgcn_exp2f(-(ub * ub));
                vals[i] = pack2bf(va, vb);
            }
            int o = 32 * c + 4 * q2;
            *reinterpret_cast<uint4_t*>(&attrU[m2 * 160 + (o ^ swz)]) = vals;
        }

        // ---- Finish next gather: distance + write other d_lds buffer ----
        if (gth && havenext) {
            float dx = ax - bx, dy = ay - by, dz = az - bz;
            d_lds[buf ^ 1][gc][gm] = sqrtf(dx * dx + dy * dy + dz * dz);
        }
        __syncthreads();   // A

        // ---- Phase 3: GEMM1 [32x320]@[320x128] ----
        f32x4 acc00 = {0.f,0.f,0.f,0.f}, acc01 = {0.f,0.f,0.f,0.f};
        f32x4 acc10 = {0.f,0.f,0.f,0.f}, acc11 = {0.f,0.f,0.f,0.f};
        #pragma unroll
        for (int ks = 0; ks < 10; ++ks) {
            int o = ks * 16 + lgrp * 4;
            short8 a0 = *reinterpret_cast<const short8*>(&attrU[lrow * 160 + (o ^ aswz)]);
            short8 a1 = *reinterpret_cast<const short8*>(&attrU[(lrow + 16) * 160 + (o ^ aswz)]);
            acc00 = __builtin_amdgcn_mfma_f32_16x16x32_bf16(a0, wb1[2 * ks],     acc00, 0, 0, 0);
            acc01 = __builtin_amdgcn_mfma_f32_16x16x32_bf16(a0, wb1[2 * ks + 1], acc01, 0, 0, 0);
            acc10 = __builtin_amdgcn_mfma_f32_16x16x32_bf16(a1, wb1[2 * ks],     acc10, 0, 0, 0);
            acc11 = __builtin_amdgcn_mfma_f32_16x16x32_bf16(a1, wb1[2 * ks + 1], acc11, 0, 0, 0);
        }

        // bias + relu + pack h to LDS (C/D layout: row=(lane>>4)*4+j, col=lane&15)
        #pragma unroll
        for (int j = 0; j < 4; ++j) {
            int r0 = lgrp * 4 + j;
            h_lds[r0][w * 32 + lrow]           = f2bf(fmaxf(acc00[j] + bv0, 0.f));
            h_lds[r0][w * 32 + 16 + lrow]      = f2bf(fmaxf(acc01[j] + bv1, 0.f));
            h_lds[r0 + 16][w * 32 + lrow]      = f2bf(fmaxf(acc10[j] + bv0, 0.f));
            h_lds[r0 + 16][w * 32 + 16 + lrow] = f2bf(fmaxf(acc11[j] + bv1, 0.f));
        }
        __syncthreads();   // B

        // ---- Phase 4: GEMM2 [32x128]@[128x128] ----
        f32x4 o00 = {0.f,0.f,0.f,0.f}, o01 = {0.f,0.f,0.f,0.f};
        f32x4 o10 = {0.f,0.f,0.f,0.f}, o11 = {0.f,0.f,0.f,0.f};
        #pragma unroll
        for (int ks = 0; ks < 4; ++ks) {
            short8 a0 = *reinterpret_cast<const short8*>(&h_lds[lrow][ks * 32 + lgrp * 8]);
            short8 a1 = *reinterpret_cast<const short8*>(&h_lds[lrow + 16][ks * 32 + lgrp * 8]);
            o00 = __builtin_amdgcn_mfma_f32_16x16x32_bf16(a0, wb2[2 * ks],     o00, 0, 0, 0);
            o01 = __builtin_amdgcn_mfma_f32_16x16x32_bf16(a0, wb2[2 * ks + 1], o01, 0, 0, 0);
            o10 = __builtin_amdgcn_mfma_f32_16x16x32_bf16(a1, wb2[2 * ks],     o10, 0, 0, 0);
            o11 = __builtin_amdgcn_mfma_f32_16x16x32_bf16(a1, wb2[2 * ks + 1], o11, 0, 0, 0);
        }

        // ---- Phase 5: bias + store fp32 ----
        const int e0 = tile * 32;
        #pragma unroll
        for (int j = 0; j < 4; ++j) {
            int r0 = lgrp * 4 + j;
            int eA = e0 + r0;
            int eB = e0 + r0 + 16;
            if (eA < E) {
                out[(size_t)eA * FOLD + w * 32 + lrow]      = o00[j] + c0;
                out[(size_t)eA * FOLD + w * 32 + 16 + lrow] = o01[j] + c1;
            }
            if (eB < E) {
                out[(size_t)eB * FOLD + w * 32 + lrow]      = o10[j] + c0;
                out[(size_t)eB * FOLD + w * 32 + 16 + lrow] = o11[j] + c1;
            }
        }

        if (!havenext) break;
        tile = next;
        buf ^= 1;
    }
}

extern "C" void kernel_launch(void* const* d_in, const int* in_sizes, int n_in,
                              void* d_out, int out_size, void* d_ws, size_t ws_size,
                              hipStream_t stream) {
    const float* lig = (const float*)d_in[0];
    const float* p0  = (const float*)d_in[1];
    const float* p1  = (const float*)d_in[2];
    const float* p2  = (const float*)d_in[3];
    const float* p3  = (const float*)d_in[4];
    const float* p4  = (const float*)d_in[5];
    const float* W1  = (const float*)d_in[6];
    const float* b1  = (const float*)d_in[7];
    const float* W2  = (const float*)d_in[8];
    const float* b2  = (const float*)d_in[9];
    const int* src   = (const int*)d_in[10];
    const int* dst   = (const int*)d_in[11];
    float* out = (float*)d_out;
    const int E = in_sizes[10];

    ushort_t* W1p = (ushort_t*)d_ws;
    ushort_t* W2p = W1p + 40960;

    pack_w<<<(40960 + 16384 + 255) / 256, 256, 0, stream>>>(W1, W2, W1p, W2p);

    int tiles = (E + 31) / 32;
    int nblk = tiles < 1024 ? tiles : 1024;
    fused<<<nblk, 256, 0, stream>>>(lig, p0, p1, p2, p3, p4, W1p, W2p,
                                    b1, b2, src, dst, out, E);
}